// Round 5
// baseline (2268.665 us; speedup 1.0000x reference)
//
#include <hip/hip_runtime.h>
#include <hip/hip_bf16.h>
#include <stdint.h>

#define NCH   16
#define NKK   32
#define KS    15
#define VOL   884736          // 96^3
#define HVOL  442368          // VOL/2
#define HBYTE 28311552        // HVOL*16ch*4B = VOL*16*2B / 2 = half of d_out bytes

typedef uint16_t u16;

__device__ __forceinline__ u16 f2bf(float f) {
    __hip_bfloat16 h = __float2bfloat16(f);            // RTNE
    return *reinterpret_cast<u16*>(&h);
}
__device__ __forceinline__ float bf2f(u16 u) { return __uint_as_float(((uint32_t)u) << 16); }
__device__ __forceinline__ float bf2f_lo(uint32_t u) { return __uint_as_float(u << 16); }
__device__ __forceinline__ float bf2f_hi(uint32_t u) { return __uint_as_float(u & 0xFFFF0000u); }

// ---------------------------------------------------------------------------
// T: x[a][b][d][c] (f32, channels-last) -> xt[c][a][b][d] (bf16, unpadded,
// channel-major, at d_out back half) AND acc[v][c] = bf16(x) (voxel-major,
// d_out front half; residual base for the reduce).
// One block per (a,b) row: coalesced float4 reads, LDS stride-17 transpose.
// ---------------------------------------------------------------------------
__global__ __launch_bounds__(256) void t_kernel(const float* __restrict__ x,
                                                u16* __restrict__ xt,
                                                u16* __restrict__ acc) {
    const int a = blockIdx.x;   // 0..95
    const int b = blockIdx.y;   // 0..95
    __shared__ float row[96 * 17];

    const float4* src = (const float4*)(x + ((size_t)(a * 96 + b) * 96) * 16);
    const int t = threadIdx.x;
    for (int i = t; i < 384; i += 256) {           // 96 vox * 16 ch, coalesced
        float4 v = src[i];
        int sx = i >> 2, c4 = (i & 3) * 4;
        float* p = &row[sx * 17 + c4];
        p[0] = v.x; p[1] = v.y; p[2] = v.z; p[3] = v.w;
    }
    __syncthreads();

    if (t < 192) {
        // xt: channel c (t/12), chunk j (t%12) of 8 d-values
        int c = t / 12, j = t - c * 12;
        u16 h[8];
        #pragma unroll
        for (int e = 0; e < 8; ++e) h[e] = f2bf(row[(8 * j + e) * 17 + c]);
        *(uint4*)(xt + (size_t)c * VOL + (size_t)(a * 96 + b) * 96 + 8 * j) =
            *(const uint4*)h;

        // acc: voxel v (t/2), channel-half h8 (8 channels)
        int v = t >> 1, h8 = (t & 1) * 8;
        u16 g[8];
        #pragma unroll
        for (int e = 0; e < 8; ++e) g[e] = f2bf(row[v * 17 + h8 + e]);
        *(uint4*)(acc + ((size_t)(a * 96 + b) * 96 + v) * 16 + h8) =
            *(const uint4*)g;
    }
}

// ---------------------------------------------------------------------------
// C: depthwise 15^3 conv (wrap in-kernel) + Gaussian growth, one k per
// blockIdx.z. Thread tile 8z x 8x (64 fp32 acc). Per (zi,dy) row: 3 aligned
// 16B chunk loads (24 bf16 window, mod-96 chunk bases precomputed per
// thread), decode, FMA against block-uniform scalar weights.
// growth (bf16) -> d_in[0] (x is dead): z>=48 half to front, z<48 to back.
// ---------------------------------------------------------------------------
__global__ __launch_bounds__(192) void c_kernel(
    const u16* __restrict__ xt, const float* __restrict__ kern,
    const float* __restrict__ mv, const float* __restrict__ sv,
    const int* __restrict__ c0, u16* __restrict__ growth) {

    const int tx = threadIdx.x;   // 0..11
    const int ty = threadIdx.y;   // 0..15
    const int zb = blockIdx.x;    // 0..11
    const int yb = blockIdx.y;    // 0..5
    const int k  = blockIdx.z;    // 0..31

    const int z0 = zb * 8;
    const int y  = yb * 16 + ty;
    const int x0 = tx * 8;

    const int ch = c0[k];
    const u16* __restrict__ chbase = xt + (size_t)ch * VOL;
    const float* __restrict__ wk = kern + k * (KS * KS * KS);

    // 3 wrap-resolved 8-element chunk offsets covering x = x0-8 .. x0+15
    int cs[3];
    #pragma unroll
    for (int c = 0; c < 3; ++c) {
        int s = x0 - 8 + 8 * c;
        if (s < 0) s += 96;
        if (s >= 96) s -= 96;
        cs[c] = s;
    }

    float acc[8][8];
    #pragma unroll
    for (int i = 0; i < 8; ++i)
        #pragma unroll
        for (int j = 0; j < 8; ++j) acc[i][j] = 0.0f;

    #pragma unroll 1
    for (int zi = 0; zi < 22; ++zi) {
        int zs = z0 + zi + 89;               // (z0+zi-7) mod 96
        if (zs >= 96) zs -= 96;
        if (zs >= 96) zs -= 96;
        const u16* __restrict__ zbase = chbase + zs * 96 * 96;
        #pragma unroll 1
        for (int dy = 0; dy < 15; ++dy) {
            int ys = y + dy + 89;            // (y+dy-7) mod 96
            if (ys >= 96) ys -= 96;
            if (ys >= 96) ys -= 96;
            const u16* rb = zbase + ys * 96;
            uint4 A = *(const uint4*)(rb + cs[0]);
            uint4 B = *(const uint4*)(rb + cs[1]);
            uint4 C = *(const uint4*)(rb + cs[2]);
            uint32_t u[12] = {A.x, A.y, A.z, A.w, B.x, B.y, B.z, B.w,
                              C.x, C.y, C.z, C.w};
            float xw[24];   // xw[i] = x at (x0 - 8 + i), wrapped
            #pragma unroll
            for (int j = 0; j < 12; ++j) {
                xw[2 * j]     = bf2f_lo(u[j]);
                xw[2 * j + 1] = bf2f_hi(u[j]);
            }
            #pragma unroll
            for (int zo = 0; zo < 8; ++zo) {
                const int dz = zi - zo;
                if (dz >= 0 && dz < KS) {              // wave-uniform guard
                    const float* __restrict__ wrow = wk + (dz * KS + dy) * KS;
                    #pragma unroll
                    for (int dx = 0; dx < KS; ++dx) {
                        const float w = wrow[dx];
                        #pragma unroll
                        for (int xo = 0; xo < 8; ++xo)
                            // tap x = x0+xo+dx-7 -> window idx xo+dx+1
                            acc[zo][xo] = fmaf(w, xw[xo + dx + 1], acc[zo][xo]);
                    }
                }
            }
        }
    }

    const float mk = mv[k];
    const float sk = sv[k];
    const float ninv = -1.0f / (2.0f * sk * sk);

    #pragma unroll
    for (int zo = 0; zo < 8; ++zo) {
        u16 h[8];
        #pragma unroll
        for (int xo = 0; xo < 8; ++xo) {
            float d = acc[zo][xo] - mk;
            float g = __expf(d * d * ninv) * 2.0f - 1.0f;
            h[xo] = f2bf(g);
        }
        const int z = z0 + zo;
        size_t idx;
        if (z >= 48) {     // gA (front of d_in): [k][vloc], vloc over z 48..95
            size_t vloc = ((size_t)(z - 48) * 96 + y) * 96 + x0;
            idx = (size_t)k * HVOL + vloc;
        } else {           // gB (back of d_in): [k][v], v over z 0..47
            size_t v = ((size_t)z * 96 + y) * 96 + x0;
            idx = (size_t)HVOL * NKK + (size_t)k * HVOL + v;
        }
        *reinterpret_cast<uint4*>(growth + idx) = *reinterpret_cast<const uint4*>(h);
    }
}

// ---------------------------------------------------------------------------
// R: segment-sum 32 growth values -> 16 channels, residual from acc (bf16),
// clip, write fp32. Used twice with disjoint regions (R1: z>=48, R2: z<48).
// ---------------------------------------------------------------------------
__global__ __launch_bounds__(256) void r_kernel(
    const u16* __restrict__ acc, const u16* __restrict__ growth,
    const int* __restrict__ c1, const float* __restrict__ Tp,
    float* __restrict__ outp) {

    const int gv = blockIdx.x * 256 + threadIdx.x;   // 0..HVOL-1 exact
    const float invT = 1.0f / Tp[0];

    float field[NCH];
    #pragma unroll
    for (int c = 0; c < NCH; ++c) field[c] = 0.0f;

    #pragma unroll 1
    for (int k = 0; k < NKK; ++k) {
        float g = bf2f(growth[(size_t)k * HVOL + gv]);
        const int ck = c1[k];    // wave-uniform
        #pragma unroll
        for (int c = 0; c < NCH; ++c)
            field[c] += (ck == c) ? g : 0.0f;
    }

    const uint4* ap = (const uint4*)(acc + (size_t)gv * 16);
    uint4 a0 = ap[0], a1 = ap[1];
    uint32_t au[8] = {a0.x, a0.y, a0.z, a0.w, a1.x, a1.y, a1.z, a1.w};

    float o[16];
    #pragma unroll
    for (int j = 0; j < 8; ++j) {
        o[2 * j]     = fminf(fmaxf(bf2f_lo(au[j]) + field[2 * j]     * invT, 0.0f), 10.0f);
        o[2 * j + 1] = fminf(fmaxf(bf2f_hi(au[j]) + field[2 * j + 1] * invT, 0.0f), 10.0f);
    }

    float4* dst = (float4*)(outp + (size_t)gv * 16);
    #pragma unroll
    for (int q = 0; q < 4; ++q)
        dst[q] = *reinterpret_cast<const float4*>(&o[4 * q]);
}

// ---------------------------------------------------------------------------
// CP: copy fp32 front-half result from d_in[0] -> d_out front half.
// ---------------------------------------------------------------------------
__global__ __launch_bounds__(256) void cp_kernel(const uint4* __restrict__ src,
                                                 uint4* __restrict__ dst) {
    const int i = blockIdx.x * 256 + threadIdx.x;   // 0..1769471 exact
    dst[i] = src[i];
}

// ---------------------------------------------------------------------------
extern "C" void kernel_launch(void* const* d_in, const int* in_sizes, int n_in,
                              void* d_out, int out_size, void* d_ws, size_t ws_size,
                              hipStream_t stream) {
    const float* x    = (const float*)d_in[0];
    const float* kern = (const float*)d_in[1];
    const float* mv   = (const float*)d_in[2];
    const float* sv   = (const float*)d_in[3];
    const float* Tp   = (const float*)d_in[4];
    const int*   c0   = (const int*)d_in[5];
    const int*   c1   = (const int*)d_in[6];

    // d_out: [0, HBYTE) = acc bf16 (then final fp32 front after CP)
    //        [HBYTE, 2*HBYTE) = xt bf16 (then final fp32 back after R1)
    u16* accb = (u16*)d_out;
    u16* xt   = (u16*)((char*)d_out + HBYTE);
    // d_in[0] becomes scratch after T (harness restores it before every launch):
    // [0, HBYTE) = growth z>=48 (then final fp32 front after R2)
    // [HBYTE, 2*HBYTE) = growth z<48
    u16* growth = (u16*)d_in[0];

    t_kernel<<<dim3(96, 96), 256, 0, stream>>>(x, xt, accb);
    c_kernel<<<dim3(12, 6, 32), dim3(12, 16), 0, stream>>>(xt, kern, mv, sv, c0, growth);
    // R1: voxels z>=48 -> fp32 into d_out back half (over dead xt)
    r_kernel<<<HVOL / 256, 256, 0, stream>>>(
        accb + (size_t)HVOL * 16, growth, c1, Tp,
        (float*)((char*)d_out + HBYTE));
    // R2: voxels z<48 -> fp32 into d_in front half (over dead growth-front)
    r_kernel<<<HVOL / 256, 256, 0, stream>>>(
        accb, growth + (size_t)HVOL * NKK, c1, Tp,
        (float*)d_in[0]);
    // CP: d_in front half -> d_out front half (over dead acc)
    cp_kernel<<<(HBYTE / 16) / 256, 256, 0, stream>>>(
        (const uint4*)d_in[0], (uint4*)d_out);
}

// Round 6
// 2252.745 us; speedup vs baseline: 1.0071x; 1.0071x over previous
//
#include <hip/hip_runtime.h>
#include <hip/hip_bf16.h>
#include <stdint.h>

#define NCH   16
#define NKK   32
#define KS    15
#define VOL   884736          // 96^3
#define HVOL  442368          // VOL/2
#define HBYTE 28311552        // HVOL*16ch*4B = half of d_out bytes

typedef uint16_t u16;

__device__ __forceinline__ u16 f2bf(float f) {
    __hip_bfloat16 h = __float2bfloat16(f);            // RTNE
    return *reinterpret_cast<u16*>(&h);
}
__device__ __forceinline__ float bf2f(u16 u) { return __uint_as_float(((uint32_t)u) << 16); }
__device__ __forceinline__ float bf2f_lo(uint32_t u) { return __uint_as_float(u << 16); }
__device__ __forceinline__ float bf2f_hi(uint32_t u) { return __uint_as_float(u & 0xFFFF0000u); }

// ---------------------------------------------------------------------------
// T: x[a][b][d][c] (f32, channels-last) -> xt[c][a][b][d] (bf16, unpadded,
// channel-major, at d_out back half) AND acc[v][c] = bf16(x) (voxel-major,
// d_out front half; residual base for the reduce).
// ---------------------------------------------------------------------------
__global__ __launch_bounds__(256) void t_kernel(const float* __restrict__ x,
                                                u16* __restrict__ xt,
                                                u16* __restrict__ acc) {
    const int a = blockIdx.x;   // 0..95
    const int b = blockIdx.y;   // 0..95
    __shared__ float row[96 * 17];

    const float4* src = (const float4*)(x + ((size_t)(a * 96 + b) * 96) * 16);
    const int t = threadIdx.x;
    for (int i = t; i < 384; i += 256) {           // 96 vox * 16 ch, coalesced
        float4 v = src[i];
        int sx = i >> 2, c4 = (i & 3) * 4;
        float* p = &row[sx * 17 + c4];
        p[0] = v.x; p[1] = v.y; p[2] = v.z; p[3] = v.w;
    }
    __syncthreads();

    if (t < 192) {
        // xt: channel c (t/12), chunk j (t%12) of 8 d-values
        int c = t / 12, j = t - c * 12;
        u16 h[8];
        #pragma unroll
        for (int e = 0; e < 8; ++e) h[e] = f2bf(row[(8 * j + e) * 17 + c]);
        *(uint4*)(xt + (size_t)c * VOL + (size_t)(a * 96 + b) * 96 + 8 * j) =
            *(const uint4*)h;

        // acc: voxel v (t/2), channel-half h8 (8 channels)
        int v = t >> 1, h8 = (t & 1) * 8;
        u16 g[8];
        #pragma unroll
        for (int e = 0; e < 8; ++e) g[e] = f2bf(row[v * 17 + h8 + e]);
        *(uint4*)(acc + ((size_t)(a * 96 + b) * 96 + v) * 16 + h8) =
            *(const uint4*)g;
    }
}

// ---------------------------------------------------------------------------
// C: depthwise 15^3 conv (wrap in-kernel) + Gaussian growth, one k per
// blockIdx.z. Thread tile 8z x 8x (64 fp32 acc). Per (zi,dy) row: 3 aligned
// 16B chunk loads (24 bf16 window), decode, FMA vs block-uniform weights.
// __launch_bounds__(192, 1): min 1 wave/EU releases the VGPR budget so
// acc[8][8] stays in VGPRs (round-5 evidence: VGPR_Count=60 < 64 live accs
// -> AGPR shuttling -> exactly 2x FMA-roofline time, VALUBusy 74%).
// growth (bf16) -> d_in[0] (x is dead): z>=48 half to front, z<48 to back.
// ---------------------------------------------------------------------------
__global__ __launch_bounds__(192, 1) void c_kernel(
    const u16* __restrict__ xt, const float* __restrict__ kern,
    const float* __restrict__ mv, const float* __restrict__ sv,
    const int* __restrict__ c0, u16* __restrict__ growth) {

    const int tx = threadIdx.x;   // 0..11
    const int ty = threadIdx.y;   // 0..15
    const int zb = blockIdx.x;    // 0..11
    const int yb = blockIdx.y;    // 0..5
    const int k  = blockIdx.z;    // 0..31

    const int z0 = zb * 8;
    const int y  = yb * 16 + ty;
    const int x0 = tx * 8;

    const int ch = c0[k];
    const u16* __restrict__ chbase = xt + (size_t)ch * VOL;
    const float* __restrict__ wk = kern + k * (KS * KS * KS);

    // 3 wrap-resolved 8-element chunk offsets covering x = x0-8 .. x0+15
    int cs[3];
    #pragma unroll
    for (int c = 0; c < 3; ++c) {
        int s = x0 - 8 + 8 * c;
        if (s < 0) s += 96;
        if (s >= 96) s -= 96;
        cs[c] = s;
    }

    float acc[8][8];
    #pragma unroll
    for (int i = 0; i < 8; ++i)
        #pragma unroll
        for (int j = 0; j < 8; ++j) acc[i][j] = 0.0f;

    #pragma unroll 1
    for (int zi = 0; zi < 22; ++zi) {
        int zs = z0 + zi + 89;               // (z0+zi-7) mod 96
        if (zs >= 96) zs -= 96;
        if (zs >= 96) zs -= 96;
        const u16* __restrict__ zbase = chbase + zs * 96 * 96;
        #pragma unroll 1
        for (int dy = 0; dy < 15; ++dy) {
            int ys = y + dy + 89;            // (y+dy-7) mod 96
            if (ys >= 96) ys -= 96;
            if (ys >= 96) ys -= 96;
            const u16* rb = zbase + ys * 96;
            uint4 A = *(const uint4*)(rb + cs[0]);
            uint4 B = *(const uint4*)(rb + cs[1]);
            uint4 C = *(const uint4*)(rb + cs[2]);
            uint32_t u[12] = {A.x, A.y, A.z, A.w, B.x, B.y, B.z, B.w,
                              C.x, C.y, C.z, C.w};
            float xw[24];   // xw[i] = x at (x0 - 8 + i), wrapped
            #pragma unroll
            for (int j = 0; j < 12; ++j) {
                xw[2 * j]     = bf2f_lo(u[j]);
                xw[2 * j + 1] = bf2f_hi(u[j]);
            }
            #pragma unroll
            for (int zo = 0; zo < 8; ++zo) {
                const int dz = zi - zo;
                if (dz >= 0 && dz < KS) {              // wave-uniform guard
                    const float* __restrict__ wrow = wk + (dz * KS + dy) * KS;
                    #pragma unroll
                    for (int dx = 0; dx < KS; ++dx) {
                        const float w = wrow[dx];
                        #pragma unroll
                        for (int xo = 0; xo < 8; ++xo)
                            acc[zo][xo] = fmaf(w, xw[xo + dx + 1], acc[zo][xo]);
                    }
                }
            }
        }
    }

    const float mk = mv[k];
    const float sk = sv[k];
    const float ninv = -1.0f / (2.0f * sk * sk);

    #pragma unroll
    for (int zo = 0; zo < 8; ++zo) {
        u16 h[8];
        #pragma unroll
        for (int xo = 0; xo < 8; ++xo) {
            float d = acc[zo][xo] - mk;
            float g = __expf(d * d * ninv) * 2.0f - 1.0f;
            h[xo] = f2bf(g);
        }
        const int z = z0 + zo;
        size_t idx;
        if (z >= 48) {     // gA (front of d_in): [k][vloc], vloc over z 48..95
            size_t vloc = ((size_t)(z - 48) * 96 + y) * 96 + x0;
            idx = (size_t)k * HVOL + vloc;
        } else {           // gB (back of d_in): [k][v], v over z 0..47
            size_t v = ((size_t)z * 96 + y) * 96 + x0;
            idx = (size_t)HVOL * NKK + (size_t)k * HVOL + v;
        }
        *reinterpret_cast<uint4*>(growth + idx) = *reinterpret_cast<const uint4*>(h);
    }
}

// ---------------------------------------------------------------------------
// R: segment-sum 32 growth values -> 16 channels, residual from acc (bf16),
// clip, write fp32. Used twice with disjoint regions (R1: z>=48, R2: z<48).
// ---------------------------------------------------------------------------
__global__ __launch_bounds__(256) void r_kernel(
    const u16* __restrict__ acc, const u16* __restrict__ growth,
    const int* __restrict__ c1, const float* __restrict__ Tp,
    float* __restrict__ outp) {

    const int gv = blockIdx.x * 256 + threadIdx.x;   // 0..HVOL-1 exact
    const float invT = 1.0f / Tp[0];

    float field[NCH];
    #pragma unroll
    for (int c = 0; c < NCH; ++c) field[c] = 0.0f;

    #pragma unroll 1
    for (int k = 0; k < NKK; ++k) {
        float g = bf2f(growth[(size_t)k * HVOL + gv]);
        const int ck = c1[k];    // wave-uniform
        #pragma unroll
        for (int c = 0; c < NCH; ++c)
            field[c] += (ck == c) ? g : 0.0f;
    }

    const uint4* ap = (const uint4*)(acc + (size_t)gv * 16);
    uint4 a0 = ap[0], a1 = ap[1];
    uint32_t au[8] = {a0.x, a0.y, a0.z, a0.w, a1.x, a1.y, a1.z, a1.w};

    float o[16];
    #pragma unroll
    for (int j = 0; j < 8; ++j) {
        o[2 * j]     = fminf(fmaxf(bf2f_lo(au[j]) + field[2 * j]     * invT, 0.0f), 10.0f);
        o[2 * j + 1] = fminf(fmaxf(bf2f_hi(au[j]) + field[2 * j + 1] * invT, 0.0f), 10.0f);
    }

    float4* dst = (float4*)(outp + (size_t)gv * 16);
    #pragma unroll
    for (int q = 0; q < 4; ++q)
        dst[q] = *reinterpret_cast<const float4*>(&o[4 * q]);
}

// ---------------------------------------------------------------------------
// CP: copy fp32 front-half result from d_in[0] -> d_out front half.
// ---------------------------------------------------------------------------
__global__ __launch_bounds__(256) void cp_kernel(const uint4* __restrict__ src,
                                                 uint4* __restrict__ dst) {
    const int i = blockIdx.x * 256 + threadIdx.x;   // 0..1769471 exact
    dst[i] = src[i];
}

// ---------------------------------------------------------------------------
extern "C" void kernel_launch(void* const* d_in, const int* in_sizes, int n_in,
                              void* d_out, int out_size, void* d_ws, size_t ws_size,
                              hipStream_t stream) {
    const float* x    = (const float*)d_in[0];
    const float* kern = (const float*)d_in[1];
    const float* mv   = (const float*)d_in[2];
    const float* sv   = (const float*)d_in[3];
    const float* Tp   = (const float*)d_in[4];
    const int*   c0   = (const int*)d_in[5];
    const int*   c1   = (const int*)d_in[6];

    // d_out: [0, HBYTE) = acc bf16 (then final fp32 front after CP)
    //        [HBYTE, 2*HBYTE) = xt bf16 (then final fp32 back after R1)
    u16* accb = (u16*)d_out;
    u16* xt   = (u16*)((char*)d_out + HBYTE);
    // d_in[0] becomes scratch after T (harness restores it before every launch):
    // [0, HBYTE) = growth z>=48 (then final fp32 front after R2)
    // [HBYTE, 2*HBYTE) = growth z<48
    u16* growth = (u16*)d_in[0];

    t_kernel<<<dim3(96, 96), 256, 0, stream>>>(x, xt, accb);
    c_kernel<<<dim3(12, 6, 32), dim3(12, 16), 0, stream>>>(xt, kern, mv, sv, c0, growth);
    // R1: voxels z>=48 -> fp32 into d_out back half (over dead xt)
    r_kernel<<<HVOL / 256, 256, 0, stream>>>(
        accb + (size_t)HVOL * 16, growth, c1, Tp,
        (float*)((char*)d_out + HBYTE));
    // R2: voxels z<48 -> fp32 into d_in front half (over dead growth-front)
    r_kernel<<<HVOL / 256, 256, 0, stream>>>(
        accb, growth + (size_t)HVOL * NKK, c1, Tp,
        (float*)d_in[0]);
    // CP: d_in front half -> d_out front half (over dead acc)
    cp_kernel<<<(HBYTE / 16) / 256, 256, 0, stream>>>(
        (const uint4*)d_in[0], (uint4*)d_out);
}

// Round 7
// 2087.682 us; speedup vs baseline: 1.0867x; 1.0791x over previous
//
#include <hip/hip_runtime.h>
#include <hip/hip_bf16.h>
#include <stdint.h>

#define NCH   16
#define NKK   32
#define KS    15
#define VOL   884736          // 96^3
#define HVOL  442368          // VOL/2
#define HBYTE 28311552        // HVOL*16ch*4B = half of d_out bytes

typedef uint16_t u16;

__device__ __forceinline__ u16 f2bf(float f) {
    __hip_bfloat16 h = __float2bfloat16(f);            // RTNE
    return *reinterpret_cast<u16*>(&h);
}
__device__ __forceinline__ float bf2f(u16 u) { return __uint_as_float(((uint32_t)u) << 16); }
__device__ __forceinline__ float bf2f_lo(uint32_t u) { return __uint_as_float(u << 16); }
__device__ __forceinline__ float bf2f_hi(uint32_t u) { return __uint_as_float(u & 0xFFFF0000u); }

// ---------------------------------------------------------------------------
// T: x[a][b][d][c] (f32, channels-last) -> xt[c][a][b][d] (bf16, unpadded,
// channel-major, at d_out back half) AND acc[v][c] = bf16(x) (voxel-major,
// d_out front half; residual base for the reduce).
// ---------------------------------------------------------------------------
__global__ __launch_bounds__(256) void t_kernel(const float* __restrict__ x,
                                                u16* __restrict__ xt,
                                                u16* __restrict__ acc) {
    const int a = blockIdx.x;   // 0..95
    const int b = blockIdx.y;   // 0..95
    __shared__ float row[96 * 17];

    const float4* src = (const float4*)(x + ((size_t)(a * 96 + b) * 96) * 16);
    const int t = threadIdx.x;
    for (int i = t; i < 384; i += 256) {           // 96 vox * 16 ch, coalesced
        float4 v = src[i];
        int sx = i >> 2, c4 = (i & 3) * 4;
        float* p = &row[sx * 17 + c4];
        p[0] = v.x; p[1] = v.y; p[2] = v.z; p[3] = v.w;
    }
    __syncthreads();

    if (t < 192) {
        // xt: channel c (t/12), chunk j (t%12) of 8 d-values
        int c = t / 12, j = t - c * 12;
        u16 h[8];
        #pragma unroll
        for (int e = 0; e < 8; ++e) h[e] = f2bf(row[(8 * j + e) * 17 + c]);
        *(uint4*)(xt + (size_t)c * VOL + (size_t)(a * 96 + b) * 96 + 8 * j) =
            *(const uint4*)h;

        // acc: voxel v (t/2), channel-half h8 (8 channels)
        int v = t >> 1, h8 = (t & 1) * 8;
        u16 g[8];
        #pragma unroll
        for (int e = 0; e < 8; ++e) g[e] = f2bf(row[v * 17 + h8 + e]);
        *(uint4*)(acc + ((size_t)(a * 96 + b) * 96 + v) * 16 + h8) =
            *(const uint4*)g;
    }
}

// ---------------------------------------------------------------------------
// C: depthwise 15^3 conv (wrap in-kernel) + Gaussian growth, one k per
// blockIdx.z. Thread tile 4z x 8x (32 fp32 acc -- r6 evidence: 8z tile's
// ~110-reg live set was split 60 VGPR + ~140 AGPR by the allocator
// (Occupancy 32%), with accvgpr shuttles costing ~0.6 ms VALU and 26% idle.
// 32 acc + 24 window + addressing ~= 90 regs fits cleanly).
// Per (zi,dy) row: 3 aligned 16B chunk loads (24 bf16 window), decode,
// FMA vs block-uniform weights. growth (bf16) -> d_in[0] (x dead after T):
// z>=48 half to front, z<48 to back.
// ---------------------------------------------------------------------------
__global__ __launch_bounds__(192, 1) void c_kernel(
    const u16* __restrict__ xt, const float* __restrict__ kern,
    const float* __restrict__ mv, const float* __restrict__ sv,
    const int* __restrict__ c0, u16* __restrict__ growth) {

    const int tx = threadIdx.x;   // 0..11
    const int ty = threadIdx.y;   // 0..15
    const int zb = blockIdx.x;    // 0..23
    const int yb = blockIdx.y;    // 0..5
    const int k  = blockIdx.z;    // 0..31

    const int z0 = zb * 4;
    const int y  = yb * 16 + ty;
    const int x0 = tx * 8;

    const int ch = c0[k];
    const u16* __restrict__ chbase = xt + (size_t)ch * VOL;
    const float* __restrict__ wk = kern + k * (KS * KS * KS);

    // 3 wrap-resolved 8-element chunk offsets covering x = x0-8 .. x0+15
    int cs[3];
    #pragma unroll
    for (int c = 0; c < 3; ++c) {
        int s = x0 - 8 + 8 * c;
        if (s < 0) s += 96;
        if (s >= 96) s -= 96;
        cs[c] = s;
    }

    float acc[4][8];
    #pragma unroll
    for (int i = 0; i < 4; ++i)
        #pragma unroll
        for (int j = 0; j < 8; ++j) acc[i][j] = 0.0f;

    #pragma unroll 1
    for (int zi = 0; zi < 18; ++zi) {        // 4 + 15 - 1
        int zs = z0 + zi + 89;               // (z0+zi-7) mod 96
        if (zs >= 96) zs -= 96;
        if (zs >= 96) zs -= 96;
        const u16* __restrict__ zbase = chbase + zs * 96 * 96;
        #pragma unroll 1
        for (int dy = 0; dy < 15; ++dy) {
            int ys = y + dy + 89;            // (y+dy-7) mod 96
            if (ys >= 96) ys -= 96;
            if (ys >= 96) ys -= 96;
            const u16* rb = zbase + ys * 96;
            uint4 A = *(const uint4*)(rb + cs[0]);
            uint4 B = *(const uint4*)(rb + cs[1]);
            uint4 C = *(const uint4*)(rb + cs[2]);
            uint32_t u[12] = {A.x, A.y, A.z, A.w, B.x, B.y, B.z, B.w,
                              C.x, C.y, C.z, C.w};
            float xw[24];   // xw[i] = x at (x0 - 8 + i), wrapped
            #pragma unroll
            for (int j = 0; j < 12; ++j) {
                xw[2 * j]     = bf2f_lo(u[j]);
                xw[2 * j + 1] = bf2f_hi(u[j]);
            }
            #pragma unroll
            for (int zo = 0; zo < 4; ++zo) {
                const int dz = zi - zo;
                if (dz >= 0 && dz < KS) {              // wave-uniform guard
                    const float* __restrict__ wrow = wk + (dz * KS + dy) * KS;
                    #pragma unroll
                    for (int dx = 0; dx < KS; ++dx) {
                        const float w = wrow[dx];
                        #pragma unroll
                        for (int xo = 0; xo < 8; ++xo)
                            acc[zo][xo] = fmaf(w, xw[xo + dx + 1], acc[zo][xo]);
                    }
                }
            }
        }
    }

    const float mk = mv[k];
    const float sk = sv[k];
    const float ninv = -1.0f / (2.0f * sk * sk);

    #pragma unroll
    for (int zo = 0; zo < 4; ++zo) {
        u16 h[8];
        #pragma unroll
        for (int xo = 0; xo < 8; ++xo) {
            float d = acc[zo][xo] - mk;
            float g = __expf(d * d * ninv) * 2.0f - 1.0f;
            h[xo] = f2bf(g);
        }
        const int z = z0 + zo;
        size_t idx;
        if (z >= 48) {     // gA (front of d_in): [k][vloc], vloc over z 48..95
            size_t vloc = ((size_t)(z - 48) * 96 + y) * 96 + x0;
            idx = (size_t)k * HVOL + vloc;
        } else {           // gB (back of d_in): [k][v], v over z 0..47
            size_t v = ((size_t)z * 96 + y) * 96 + x0;
            idx = (size_t)HVOL * NKK + (size_t)k * HVOL + v;
        }
        *reinterpret_cast<uint4*>(growth + idx) = *reinterpret_cast<const uint4*>(h);
    }
}

// ---------------------------------------------------------------------------
// R: segment-sum 32 growth values -> 16 channels, residual from acc (bf16),
// clip, write fp32. Used twice with disjoint regions (R1: z>=48, R2: z<48).
// ---------------------------------------------------------------------------
__global__ __launch_bounds__(256) void r_kernel(
    const u16* __restrict__ acc, const u16* __restrict__ growth,
    const int* __restrict__ c1, const float* __restrict__ Tp,
    float* __restrict__ outp) {

    const int gv = blockIdx.x * 256 + threadIdx.x;   // 0..HVOL-1 exact
    const float invT = 1.0f / Tp[0];

    float field[NCH];
    #pragma unroll
    for (int c = 0; c < NCH; ++c) field[c] = 0.0f;

    #pragma unroll 1
    for (int k = 0; k < NKK; ++k) {
        float g = bf2f(growth[(size_t)k * HVOL + gv]);
        const int ck = c1[k];    // wave-uniform
        #pragma unroll
        for (int c = 0; c < NCH; ++c)
            field[c] += (ck == c) ? g : 0.0f;
    }

    const uint4* ap = (const uint4*)(acc + (size_t)gv * 16);
    uint4 a0 = ap[0], a1 = ap[1];
    uint32_t au[8] = {a0.x, a0.y, a0.z, a0.w, a1.x, a1.y, a1.z, a1.w};

    float o[16];
    #pragma unroll
    for (int j = 0; j < 8; ++j) {
        o[2 * j]     = fminf(fmaxf(bf2f_lo(au[j]) + field[2 * j]     * invT, 0.0f), 10.0f);
        o[2 * j + 1] = fminf(fmaxf(bf2f_hi(au[j]) + field[2 * j + 1] * invT, 0.0f), 10.0f);
    }

    float4* dst = (float4*)(outp + (size_t)gv * 16);
    #pragma unroll
    for (int q = 0; q < 4; ++q)
        dst[q] = *reinterpret_cast<const float4*>(&o[4 * q]);
}

// ---------------------------------------------------------------------------
// CP: copy fp32 front-half result from d_in[0] -> d_out front half.
// ---------------------------------------------------------------------------
__global__ __launch_bounds__(256) void cp_kernel(const uint4* __restrict__ src,
                                                 uint4* __restrict__ dst) {
    const int i = blockIdx.x * 256 + threadIdx.x;   // 0..1769471 exact
    dst[i] = src[i];
}

// ---------------------------------------------------------------------------
extern "C" void kernel_launch(void* const* d_in, const int* in_sizes, int n_in,
                              void* d_out, int out_size, void* d_ws, size_t ws_size,
                              hipStream_t stream) {
    const float* x    = (const float*)d_in[0];
    const float* kern = (const float*)d_in[1];
    const float* mv   = (const float*)d_in[2];
    const float* sv   = (const float*)d_in[3];
    const float* Tp   = (const float*)d_in[4];
    const int*   c0   = (const int*)d_in[5];
    const int*   c1   = (const int*)d_in[6];

    // d_out: [0, HBYTE) = acc bf16 (then final fp32 front after CP)
    //        [HBYTE, 2*HBYTE) = xt bf16 (then final fp32 back after R1)
    u16* accb = (u16*)d_out;
    u16* xt   = (u16*)((char*)d_out + HBYTE);
    // d_in[0] becomes scratch after T (harness restores it before every launch):
    // [0, HBYTE) = growth z>=48 (then final fp32 front after R2)
    // [HBYTE, 2*HBYTE) = growth z<48
    u16* growth = (u16*)d_in[0];

    t_kernel<<<dim3(96, 96), 256, 0, stream>>>(x, xt, accb);
    c_kernel<<<dim3(24, 6, 32), dim3(12, 16), 0, stream>>>(xt, kern, mv, sv, c0, growth);
    // R1: voxels z>=48 -> fp32 into d_out back half (over dead xt)
    r_kernel<<<HVOL / 256, 256, 0, stream>>>(
        accb + (size_t)HVOL * 16, growth, c1, Tp,
        (float*)((char*)d_out + HBYTE));
    // R2: voxels z<48 -> fp32 into d_in front half (over dead growth-front)
    r_kernel<<<HVOL / 256, 256, 0, stream>>>(
        accb, growth + (size_t)HVOL * NKK, c1, Tp,
        (float*)d_in[0]);
    // CP: d_in front half -> d_out front half (over dead acc)
    cp_kernel<<<(HBYTE / 16) / 256, 256, 0, stream>>>(
        (const uint4*)d_in[0], (uint4*)d_out);
}

// Round 9
// 1764.504 us; speedup vs baseline: 1.2857x; 1.1832x over previous
//
#include <hip/hip_runtime.h>
#include <hip/hip_bf16.h>
#include <stdint.h>

#define NCH   16
#define NKK   32
#define KS    15
#define VOL   884736          // 96^3
#define HVOL  442368          // VOL/2
#define HBYTE 28311552        // half of d_out bytes
#define NPAIR 48              // y-pairs per z-plane
#define WPN   1800            // 15dz * 8pr * 15dx packed-weight words (par0)

typedef uint16_t u16;
typedef _Float16 h2 __attribute__((ext_vector_type(2)));     // for fdot2
typedef __fp16   g2 __attribute__((ext_vector_type(2)));     // cvt_pkrtz result
union U32H2 { uint32_t u; h2 h; g2 g; };

__device__ __forceinline__ u16 f2bf(float f) {
    __hip_bfloat16 h = __float2bfloat16(f);            // RTNE
    return *reinterpret_cast<u16*>(&h);
}
__device__ __forceinline__ float bf2f(u16 u) { return __uint_as_float(((uint32_t)u) << 16); }
__device__ __forceinline__ float bf2f_lo(uint32_t u) { return __uint_as_float(u << 16); }
__device__ __forceinline__ float bf2f_hi(uint32_t u) { return __uint_as_float(u & 0xFFFF0000u); }

// ---------------------------------------------------------------------------
// W: pack weights into f16 dy-pairs, scaled x1024 (avoids f16 subnormals:
// raw w ~ 3e-4). par0 table only: pair pr = (w[2pr], w[2pr+1]), w[15]:=0.
// Written IN-PLACE over kern slot k (block k reads its slot to LDS first;
// harness restores d_in before every launch). par1 derived in c_kernel LDS.
// ---------------------------------------------------------------------------
__global__ __launch_bounds__(256) void w_kernel(float* __restrict__ kern) {
    const int k = blockIdx.x;
    __shared__ float w[KS * KS * KS];                  // 13.5 KB
    float* slot = kern + (size_t)k * (KS * KS * KS);
    for (int i = threadIdx.x; i < KS * KS * KS; i += 256) w[i] = slot[i];
    __syncthreads();
    uint32_t* dst = (uint32_t*)slot;                   // 1800 u32 = 7.2 KB < slot
    for (int i = threadIdx.x; i < WPN; i += 256) {
        int dx = i % 15, pr = (i / 15) % 8, dz = i / 120;
        float a = w[(dz * 15 + 2 * pr) * 15 + dx] * 1024.0f;
        float b = (2 * pr + 1 < 15) ? w[(dz * 15 + 2 * pr + 1) * 15 + dx] * 1024.0f : 0.0f;
        U32H2 u; u.g = __builtin_amdgcn_cvt_pkrtz(a, b);
        dst[i] = u.u;
    }
}

// ---------------------------------------------------------------------------
// T: x[z][y][x][c] (f32) -> xt2[c][z][p][x] (u32 = packed f16 pair of rows
// y=2p, y=2p+1) at d_out back half, AND acc[v][c] = bf16(x) at d_out front
// (residual base). One block per (z, p): 2 source rows staged in LDS.
// ---------------------------------------------------------------------------
__global__ __launch_bounds__(256) void t_kernel(const float* __restrict__ x,
                                                uint32_t* __restrict__ xt2,
                                                u16* __restrict__ acc) {
    const int z = blockIdx.x;   // 0..95
    const int p = blockIdx.y;   // 0..47
    __shared__ float rows[2][96 * 17];

    const float4* src = (const float4*)(x + ((size_t)(z * 96 + 2 * p) * 96) * 16);
    for (int i = threadIdx.x; i < 768; i += 256) {     // 2 rows * 384 float4
        int r = i >= 384;
        int j = i - r * 384;
        float4 v = src[i];
        int sx = j >> 2, c4 = (j & 3) * 4;
        float* pp = &rows[r][sx * 17 + c4];
        pp[0] = v.x; pp[1] = v.y; pp[2] = v.z; pp[3] = v.w;
    }
    __syncthreads();

    {   // xt2: 16 c x 96 x packed pairs; thread: c = t/16, 6 x-values
        int c = threadIdx.x >> 4, j = threadIdx.x & 15;
        uint32_t* dst = xt2 + (((size_t)c * 96 + z) * NPAIR + p) * 96 + 6 * j;
        #pragma unroll
        for (int e = 0; e < 6; ++e) {
            int xx = 6 * j + e;
            U32H2 u; u.g = __builtin_amdgcn_cvt_pkrtz(rows[0][xx * 17 + c],
                                                      rows[1][xx * 17 + c]);
            dst[e] = u.u;
        }
    }
    if (threadIdx.x < 192) {    // acc: 192 voxels x 16 ch bf16
        int r = threadIdx.x >= 96;
        int xx = threadIdx.x - r * 96;
        u16 h[16];
        #pragma unroll
        for (int c = 0; c < 16; ++c) h[c] = f2bf(rows[r][xx * 17 + c]);
        uint4* dst = (uint4*)(acc + ((size_t)(z * 96 + 2 * p + r) * 96 + xx) * 16);
        dst[0] = *(const uint4*)(&h[0]);
        dst[1] = *(const uint4*)(&h[8]);
    }
}

// ---------------------------------------------------------------------------
// C: depthwise 15^3 conv via v_dot2_f32_f16 (dy-paired) + Gaussian growth.
// Thread tile 4z x 8x. Per (zi, pair-row): 6 uint4 loads = 24 packed-pair
// window regs (no decode), then per valid zo: 15 ds_read (weight pair, 2-way
// broadcast) x 8 dot2. Weight tables [par][dz][pr][dx] in LDS; par1 derived
// from par0 at start. Potential accumulated x1024 (weight scale).
// ---------------------------------------------------------------------------
__global__ __launch_bounds__(192, 1) void c_kernel(
    const uint32_t* __restrict__ xt2, const float* __restrict__ kern,
    const float* __restrict__ mv, const float* __restrict__ sv,
    const int* __restrict__ c0, u16* __restrict__ growth) {

    const int tx = threadIdx.x;   // 0..11
    const int ty = threadIdx.y;   // 0..15
    const int zb = blockIdx.x;    // 0..23
    const int yb = blockIdx.y;    // 0..5
    const int k  = blockIdx.z;    // 0..31

    __shared__ uint32_t lw[2 * WPN];   // 14.4 KB: [par][dz][pr][dx]

    const uint32_t* wp0 = (const uint32_t*)(kern + (size_t)k * (KS * KS * KS));
    const int tid = ty * 12 + tx;
    for (int i = tid; i < WPN; i += 192) lw[i] = wp0[i];
    __syncthreads();
    // par1[pr] = (w[2pr-1], w[2pr]) = (hi of par0[pr-1]) | (lo of par0[pr])<<16
    for (int i = tid; i < WPN; i += 192) {
        int pr = (i / 15) % 8;
        uint32_t lo = lw[i];
        uint32_t hs = (pr == 0) ? 0u : lw[i - 15];
        lw[WPN + i] = (hs >> 16) | (lo << 16);
    }
    __syncthreads();

    const int z0 = zb * 4;
    const int y  = yb * 16 + ty;
    const int x0 = tx * 8;
    const int ch = c0[k];

    int s0 = y + 89; if (s0 >= 96) s0 -= 96;       // first tap row (dy=0)
    const int par = s0 & 1;
    const int pstart = s0 >> 1;
    const uint32_t* __restrict__ lwp = &lw[par * WPN];

    int cs[3];
    #pragma unroll
    for (int c = 0; c < 3; ++c) {
        int s = x0 - 8 + 8 * c;
        if (s < 0) s += 96;
        if (s >= 96) s -= 96;
        cs[c] = s;
    }

    const uint32_t* __restrict__ chb = xt2 + (size_t)ch * 96 * NPAIR * 96;

    float acc[4][8];
    #pragma unroll
    for (int i = 0; i < 4; ++i)
        #pragma unroll
        for (int j = 0; j < 8; ++j) acc[i][j] = 0.0f;

    #pragma unroll 1
    for (int zi = 0; zi < 18; ++zi) {
        int zs = z0 + zi + 89;
        if (zs >= 96) zs -= 96;
        if (zs >= 96) zs -= 96;
        const uint32_t* __restrict__ zrow = chb + zs * (NPAIR * 96);
        #pragma unroll 1
        for (int pr = 0; pr < 8; ++pr) {
            int pg = pstart + pr; if (pg >= NPAIR) pg -= NPAIR;
            const uint32_t* rb = zrow + pg * 96;
            uint32_t xw[24];   // packed pairs, x = x0-8 .. x0+15
            #pragma unroll
            for (int c = 0; c < 3; ++c) {
                uint4 A = *(const uint4*)(rb + cs[c]);
                uint4 B = *(const uint4*)(rb + cs[c] + 4);
                xw[8*c+0] = A.x; xw[8*c+1] = A.y; xw[8*c+2] = A.z; xw[8*c+3] = A.w;
                xw[8*c+4] = B.x; xw[8*c+5] = B.y; xw[8*c+6] = B.z; xw[8*c+7] = B.w;
            }
            #pragma unroll
            for (int zo = 0; zo < 4; ++zo) {
                const int dz = zi - zo;
                if (dz >= 0 && dz < KS) {              // wave-uniform guard
                    const uint32_t* __restrict__ wrow = &lwp[(dz * 8 + pr) * 15];
                    #pragma unroll
                    for (int dx = 0; dx < 15; ++dx) {
                        U32H2 wv; wv.u = wrow[dx];
                        #pragma unroll
                        for (int xo = 0; xo < 8; ++xo) {
                            U32H2 xv; xv.u = xw[xo + dx + 1];
                            acc[zo][xo] = __builtin_amdgcn_fdot2(xv.h, wv.h,
                                                                acc[zo][xo], false);
                        }
                    }
                }
            }
        }
    }

    const float mk = mv[k];
    const float sk = sv[k];
    const float ninv = -1.0f / (2.0f * sk * sk);

    #pragma unroll
    for (int zo = 0; zo < 4; ++zo) {
        u16 h[8];
        #pragma unroll
        for (int xo = 0; xo < 8; ++xo) {
            float pot = acc[zo][xo] * (1.0f / 1024.0f);   // undo weight scale
            float d = pot - mk;
            float g = __expf(d * d * ninv) * 2.0f - 1.0f;
            h[xo] = f2bf(g);
        }
        const int z = z0 + zo;
        size_t idx;
        if (z >= 48) {     // gA (front of d_in): z 48..95
            size_t vloc = ((size_t)(z - 48) * 96 + y) * 96 + x0;
            idx = (size_t)k * HVOL + vloc;
        } else {           // gB (back of d_in): z 0..47
            size_t v = ((size_t)z * 96 + y) * 96 + x0;
            idx = (size_t)HVOL * NKK + (size_t)k * HVOL + v;
        }
        *reinterpret_cast<uint4*>(growth + idx) = *reinterpret_cast<const uint4*>(h);
    }
}

// ---------------------------------------------------------------------------
// R: segment-sum 32 growth values -> 16 channels, residual from acc (bf16),
// clip, write fp32. Used twice with disjoint regions (R1: z>=48, R2: z<48).
// ---------------------------------------------------------------------------
__global__ __launch_bounds__(256) void r_kernel(
    const u16* __restrict__ acc, const u16* __restrict__ growth,
    const int* __restrict__ c1, const float* __restrict__ Tp,
    float* __restrict__ outp) {

    const int gv = blockIdx.x * 256 + threadIdx.x;   // 0..HVOL-1 exact
    const float invT = 1.0f / Tp[0];

    float field[NCH];
    #pragma unroll
    for (int c = 0; c < NCH; ++c) field[c] = 0.0f;

    #pragma unroll 1
    for (int k = 0; k < NKK; ++k) {
        float g = bf2f(growth[(size_t)k * HVOL + gv]);
        const int ck = c1[k];    // wave-uniform
        #pragma unroll
        for (int c = 0; c < NCH; ++c)
            field[c] += (ck == c) ? g : 0.0f;
    }

    const uint4* ap = (const uint4*)(acc + (size_t)gv * 16);
    uint4 a0 = ap[0], a1 = ap[1];
    uint32_t au[8] = {a0.x, a0.y, a0.z, a0.w, a1.x, a1.y, a1.z, a1.w};

    float o[16];
    #pragma unroll
    for (int j = 0; j < 8; ++j) {
        o[2 * j]     = fminf(fmaxf(bf2f_lo(au[j]) + field[2 * j]     * invT, 0.0f), 10.0f);
        o[2 * j + 1] = fminf(fmaxf(bf2f_hi(au[j]) + field[2 * j + 1] * invT, 0.0f), 10.0f);
    }

    float4* dst = (float4*)(outp + (size_t)gv * 16);
    #pragma unroll
    for (int q = 0; q < 4; ++q)
        dst[q] = *reinterpret_cast<const float4*>(&o[4 * q]);
}

// ---------------------------------------------------------------------------
// CP: copy fp32 front-half result from d_in[0] -> d_out front half.
// ---------------------------------------------------------------------------
__global__ __launch_bounds__(256) void cp_kernel(const uint4* __restrict__ src,
                                                 uint4* __restrict__ dst) {
    const int i = blockIdx.x * 256 + threadIdx.x;   // exact
    dst[i] = src[i];
}

// ---------------------------------------------------------------------------
extern "C" void kernel_launch(void* const* d_in, const int* in_sizes, int n_in,
                              void* d_out, int out_size, void* d_ws, size_t ws_size,
                              hipStream_t stream) {
    const float* x    = (const float*)d_in[0];
    float*       kern = (float*)d_in[1];
    const float* mv   = (const float*)d_in[2];
    const float* sv   = (const float*)d_in[3];
    const float* Tp   = (const float*)d_in[4];
    const int*   c0   = (const int*)d_in[5];
    const int*   c1   = (const int*)d_in[6];

    // d_out: [0, HBYTE) = acc bf16 (final fp32 front after CP)
    //        [HBYTE, 2*HBYTE) = xt2 packed f16 pairs (final fp32 back after R1)
    u16*      accb = (u16*)d_out;
    uint32_t* xt2  = (uint32_t*)((char*)d_out + HBYTE);
    // d_in[0] scratch after T: [0,HBYTE) growth z>=48; [HBYTE,2H) growth z<48
    u16* growth = (u16*)d_in[0];

    w_kernel<<<NKK, 256, 0, stream>>>(kern);
    t_kernel<<<dim3(96, 48), 256, 0, stream>>>(x, xt2, accb);
    c_kernel<<<dim3(24, 6, 32), dim3(12, 16), 0, stream>>>(xt2, kern, mv, sv, c0, growth);
    // R1: z>=48 -> fp32 into d_out back half (over dead xt2)
    r_kernel<<<HVOL / 256, 256, 0, stream>>>(
        accb + (size_t)HVOL * 16, growth, c1, Tp,
        (float*)((char*)d_out + HBYTE));
    // R2: z<48 -> fp32 into d_in front half (over dead growth-front)
    r_kernel<<<HVOL / 256, 256, 0, stream>>>(
        accb, growth + (size_t)HVOL * NKK, c1, Tp,
        (float*)d_in[0]);
    // CP: d_in front half -> d_out front half (over dead acc)
    cp_kernel<<<(HBYTE / 16) / 256, 256, 0, stream>>>(
        (const uint4*)d_in[0], (uint4*)d_out);
}

// Round 10
// 706.665 us; speedup vs baseline: 3.2104x; 2.4969x over previous
//
#include <hip/hip_runtime.h>
#include <hip/hip_bf16.h>
#include <stdint.h>

#define NCH    16
#define NKK    32
#define KS     15
#define VOL    884736          // 96^3
#define HVOL   442368          // VOL/2
#define HBYTE  28311552        // half of d_out / d_in[0] bytes
#define NFRAG  225             // 15 dy * 15 dz A-fragments per kernel

typedef uint16_t u16;
typedef short bfx8 __attribute__((ext_vector_type(8)));   // 8 bf16 raw (4 VGPR)
typedef float fx4  __attribute__((ext_vector_type(4)));   // MFMA C/D

__device__ __forceinline__ u16 f2bf(float f) {
    __hip_bfloat16 h = __float2bfloat16(f);               // RTNE
    return *reinterpret_cast<u16*>(&h);
}
__device__ __forceinline__ float bf2f_lo(uint32_t u) { return __uint_as_float(u << 16); }
__device__ __forceinline__ float bf2f_hi(uint32_t u) { return __uint_as_float(u & 0xFFFF0000u); }

// ---------------------------------------------------------------------------
// T: x[z][y][x][c] (f32, channels-last) -> xt[c][z][y][x] (bf16, unpadded,
// d_out back half) AND acc[v][c] = bf16(x) (voxel-major, d_out front half,
// residual base). One block per (z,y) row; LDS stride-17 transpose.
// ---------------------------------------------------------------------------
__global__ __launch_bounds__(256) void t_kernel(const float* __restrict__ x,
                                                u16* __restrict__ xt,
                                                u16* __restrict__ acc) {
    const int z = blockIdx.x;   // 0..95
    const int y = blockIdx.y;   // 0..95
    __shared__ float row[96 * 17];

    const float4* src = (const float4*)(x + ((size_t)(z * 96 + y) * 96) * 16);
    const int t = threadIdx.x;
    for (int i = t; i < 384; i += 256) {       // 96 vox * 16 ch, coalesced
        float4 v = src[i];
        int sx = i >> 2, c4 = (i & 3) * 4;
        float* p = &row[sx * 17 + c4];
        p[0] = v.x; p[1] = v.y; p[2] = v.z; p[3] = v.w;
    }
    __syncthreads();

    if (t < 192) {
        // xt: channel c = t/12, chunk j = t%12 of 8 x-values
        int c = t / 12, j = t - c * 12;
        u16 h[8];
        #pragma unroll
        for (int e = 0; e < 8; ++e) h[e] = f2bf(row[(8 * j + e) * 17 + c]);
        *(uint4*)(xt + (((size_t)c * 96 + z) * 96 + y) * 96 + 8 * j) = *(const uint4*)h;

        // acc: voxel x-pos t>>1, channel-half (t&1)*8
        int xx = t >> 1, h8 = (t & 1) * 8;
        u16 g[8];
        #pragma unroll
        for (int e = 0; e < 8; ++e) g[e] = f2bf(row[xx * 17 + h8 + e]);
        *(uint4*)(acc + ((size_t)(z * 96 + y) * 96 + xx) * 16 + h8) = *(const uint4*)g;
    }
}

// ---------------------------------------------------------------------------
// W: build Toeplitz A-fragments for mfma_f32_16x16x32_bf16.
// A[m][kk] = w[dz][dy][kk-m-1] if 0 <= kk-m-1 < 15 else 0 (window X[x0-8+kk]).
// Lane l: m = l&15, kk = (l>>4)*8 + e. Layout afrag[k][dy*15+dz][l][8] bf16
// (7.37 MB), written into d_in[0] front (x dead after T).
// ---------------------------------------------------------------------------
__global__ __launch_bounds__(256) void w_kernel(const float* __restrict__ kern,
                                                u16* __restrict__ afrag) {
    const int k = blockIdx.x;
    __shared__ float w[KS * KS * KS];          // 13.5 KB
    const float* slot = kern + (size_t)k * (KS * KS * KS);
    for (int i = threadIdx.x; i < KS * KS * KS; i += 256) w[i] = slot[i];
    __syncthreads();

    for (int i = threadIdx.x; i < NFRAG * 64; i += 256) {
        int l = i & 63;
        int f = i >> 6;                        // f = dy*15 + dz
        int dy = f / 15, dz = f - dy * 15;
        int m = l & 15, kb = l >> 4;
        u16 h[8];
        #pragma unroll
        for (int e = 0; e < 8; ++e) {
            int dx = kb * 8 + e - m - 1;
            float v = (dx >= 0 && dx < KS) ? w[(dz * KS + dy) * KS + dx] : 0.0f;
            h[e] = f2bf(v);
        }
        *(uint4*)(afrag + ((size_t)(k * NFRAG + f) * 64 + l) * 8) = *(const uint4*)h;
    }
}

// ---------------------------------------------------------------------------
// C: depthwise 15^3 conv on matrix cores + Gaussian growth -> int8.
// Block = 16x * 16y * 16z outputs for kernel k; 4 waves = 4 z-quarters.
// LDS X tile 30z * 30y * 40-stride bf16 (70.3 KB, wrap resolved at stage).
// Per dy: ring-load 15 A-frags (60 VGPR), then 18 zs * {1 B ds_read_b128,
// up to 4 MFMA reusing B across zo}. 900 MFMA / wave.
// D mapping (m89-verified): col=lane&15 (y), row=(lane>>4)*4+r (x).
// ---------------------------------------------------------------------------
__global__ __launch_bounds__(256) void c_kernel(
    const u16* __restrict__ xt, const u16* __restrict__ afrag,
    const float* __restrict__ mv, const float* __restrict__ sv,
    const int* __restrict__ c0, int8_t* __restrict__ growth) {

    const int lane = threadIdx.x;          // 0..63
    const int wave = threadIdx.y;          // 0..3
    const int bz = blockIdx.z % 6;
    const int k  = blockIdx.z / 6;
    const int xw = blockIdx.x * 16, yw = blockIdx.y * 16, zw = bz * 16;
    const int ch = c0[k];

    __shared__ u16 Xs[30 * 30 * 40];       // 70.3 KB

    // stage X tile: rows (zl, yl) in [0,30)^2, 32 x-values as 4 wrapped chunks
    const int tid = wave * 64 + lane;
    const u16* __restrict__ chb = xt + (size_t)ch * VOL;
    for (int r = tid; r < 900; r += 256) {
        int zl = r / 30, yl = r - zl * 30;
        int zg = zw - 7 + zl; if (zg < 0) zg += 96; else if (zg >= 96) zg -= 96;
        int yg = yw - 7 + yl; if (yg < 0) yg += 96; else if (yg >= 96) yg -= 96;
        const u16* src = chb + ((size_t)zg * 96 + yg) * 96;
        u16* dst = &Xs[(zl * 30 + yl) * 40];
        #pragma unroll
        for (int c = 0; c < 4; ++c) {
            int xb = xw - 8 + 8 * c; if (xb < 0) xb += 96; else if (xb >= 96) xb -= 96;
            *(uint4*)(dst + 8 * c) = *(const uint4*)(src + xb);
        }
    }
    __syncthreads();

    fx4 acc[4];
    #pragma unroll
    for (int zo = 0; zo < 4; ++zo) acc[zo] = (fx4){0.f, 0.f, 0.f, 0.f};

    const u16* __restrict__ afk = afrag + (size_t)k * NFRAG * 64 * 8;
    const int n = lane & 15, kb = lane >> 4;

    #pragma unroll 1
    for (int dy = 0; dy < 15; ++dy) {
        bfx8 ring[15];
        #pragma unroll
        for (int dz = 0; dz < 15; ++dz)
            ring[dz] = *(const bfx8*)(afk + ((size_t)(dy * 15 + dz) * 64 + lane) * 8);
        #pragma unroll
        for (int zs = 0; zs < 18; ++zs) {
            bfx8 bfrag = *(const bfx8*)(&Xs[((wave * 4 + zs) * 30 + n + dy) * 40 + kb * 8]);
            #pragma unroll
            for (int zo = 0; zo < 4; ++zo) {
                int dz = zs - zo;
                if (dz >= 0 && dz < 15)
                    acc[zo] = __builtin_amdgcn_mfma_f32_16x16x32_bf16(
                        ring[dz], bfrag, acc[zo], 0, 0, 0);
            }
        }
    }

    const float mk = mv[k], sk = sv[k];
    const float ninv = -1.0f / (2.0f * sk * sk);

    #pragma unroll
    for (int zo = 0; zo < 4; ++zo) {
        uint32_t pack = 0;
        #pragma unroll
        for (int r = 0; r < 4; ++r) {
            float d = acc[zo][r] - mk;
            float g = __expf(d * d * ninv) * 2.0f - 1.0f;
            int q = __float2int_rn(g * 127.0f);
            q = max(-127, min(127, q));
            pack |= ((uint32_t)(q & 255)) << (8 * r);
        }
        int zg = zw + wave * 4 + zo;
        size_t off = (size_t)k * VOL + (((size_t)zg * 96 + yw + n) * 96 + xw + kb * 4);
        *(uint32_t*)(growth + off) = pack;    // 4 consecutive x, 4B aligned
    }
}

// ---------------------------------------------------------------------------
// R: segment-sum 32 int8 growth -> 16 channels, residual from acc (bf16),
// clip, write fp32. Two launches with disjoint output regions.
// ---------------------------------------------------------------------------
__global__ __launch_bounds__(256) void r_kernel(
    const u16* __restrict__ acc, const int8_t* __restrict__ growth,
    const int* __restrict__ c1, const float* __restrict__ Tp,
    float* __restrict__ outp, int vbase) {

    const int gv = blockIdx.x * 256 + threadIdx.x;   // 0..HVOL-1 exact
    const int v  = vbase + gv;
    const float invT = 1.0f / Tp[0];

    float field[NCH];
    #pragma unroll
    for (int c = 0; c < NCH; ++c) field[c] = 0.0f;

    #pragma unroll 1
    for (int k = 0; k < NKK; ++k) {
        float g = (float)growth[(size_t)k * VOL + v] * (1.0f / 127.0f);
        const int ck = c1[k];    // wave-uniform
        #pragma unroll
        for (int c = 0; c < NCH; ++c)
            field[c] += (ck == c) ? g : 0.0f;
    }

    const uint4* ap = (const uint4*)(acc + (size_t)v * 16);
    uint4 a0 = ap[0], a1 = ap[1];
    uint32_t au[8] = {a0.x, a0.y, a0.z, a0.w, a1.x, a1.y, a1.z, a1.w};

    float o[16];
    #pragma unroll
    for (int j = 0; j < 8; ++j) {
        o[2 * j]     = fminf(fmaxf(bf2f_lo(au[j]) + field[2 * j]     * invT, 0.0f), 10.0f);
        o[2 * j + 1] = fminf(fmaxf(bf2f_hi(au[j]) + field[2 * j + 1] * invT, 0.0f), 10.0f);
    }

    float4* dst = (float4*)(outp + (size_t)gv * 16);
    #pragma unroll
    for (int q = 0; q < 4; ++q)
        dst[q] = *reinterpret_cast<const float4*>(&o[4 * q]);
}

// ---------------------------------------------------------------------------
__global__ __launch_bounds__(256) void cp_kernel(const uint4* __restrict__ src,
                                                 uint4* __restrict__ dst) {
    const int i = blockIdx.x * 256 + threadIdx.x;   // exact
    dst[i] = src[i];
}

// ---------------------------------------------------------------------------
extern "C" void kernel_launch(void* const* d_in, const int* in_sizes, int n_in,
                              void* d_out, int out_size, void* d_ws, size_t ws_size,
                              hipStream_t stream) {
    const float* x    = (const float*)d_in[0];
    const float* kern = (const float*)d_in[1];
    const float* mv   = (const float*)d_in[2];
    const float* sv   = (const float*)d_in[3];
    const float* Tp   = (const float*)d_in[4];
    const int*   c0   = (const int*)d_in[5];
    const int*   c1   = (const int*)d_in[6];

    // d_out: [0,HBYTE) = acc bf16 (-> final fp32 front after CP)
    //        [HBYTE,2H) = xt bf16  (-> final fp32 back after R1)
    u16* accb = (u16*)d_out;
    u16* xt   = (u16*)((char*)d_out + HBYTE);
    // d_in[0] scratch after T: [0,7.4MB) A-frags (-> R2 fp32 output region),
    //                          [HBYTE,2H) growth int8 [k][VOL]
    u16*    afrag   = (u16*)d_in[0];
    int8_t* growth8 = (int8_t*)d_in[0] + HBYTE;

    t_kernel<<<dim3(96, 96), 256, 0, stream>>>(x, xt, accb);
    w_kernel<<<NKK, 256, 0, stream>>>(kern, afrag);
    c_kernel<<<dim3(6, 6, 6 * NKK), dim3(64, 4), 0, stream>>>(
        xt, afrag, mv, sv, c0, growth8);
    // R1: voxels z>=48 -> fp32 into d_out back half (over dead xt)
    r_kernel<<<HVOL / 256, 256, 0, stream>>>(
        accb, growth8, c1, Tp, (float*)((char*)d_out + HBYTE), HVOL);
    // R2: voxels z<48 -> fp32 into d_in front (over dead A-frags)
    r_kernel<<<HVOL / 256, 256, 0, stream>>>(
        accb, growth8, c1, Tp, (float*)d_in[0], 0);
    // CP: d_in front half -> d_out front half (over dead acc)
    cp_kernel<<<(HBYTE / 16) / 256, 256, 0, stream>>>(
        (const uint4*)d_in[0], (uint4*)d_out);
}